// Round 7
// baseline (765.049 us; speedup 1.0000x reference)
//
#include <hip/hip_runtime.h>

typedef __attribute__((ext_vector_type(8))) short short8;
typedef __attribute__((ext_vector_type(4))) float f32x4;
typedef __attribute__((ext_vector_type(16))) float f32x16;
typedef unsigned int uint;

constexpr int B = 4, C = 128, H = 192, W = 320;
constexpr int HW_ = H * W;

__device__ __forceinline__ unsigned short f2bf(float x) {
    uint u = __float_as_uint(x);
    u += 0x7fffu + ((u >> 16) & 1u);
    return (unsigned short)(u >> 16);
}
__device__ __forceinline__ uint pack2bf(float a, float b) {
    return (uint)f2bf(a) | ((uint)f2bf(b) << 16);
}

// ---------------------------------------------------------------------------
// 1) up_flow in fp64 (feeds floor()/mask decisions downstream)
// ---------------------------------------------------------------------------
__global__ __launch_bounds__(256) void upflow_kernel(
    const float* __restrict__ flow, const float* __restrict__ up_w,
    double* __restrict__ flow_up)
{
#pragma clang fp contract(off)
    int idx = blockIdx.x * 256 + threadIdx.x;
    if (idx >= B * 2 * HW_) return;
    int x = idx % W;
    int y = (idx / W) % H;
    int c = (idx / HW_) % 2;
    int b = idx / (2 * HW_);
    double acc = 0.0;
    #pragma unroll
    for (int ky = 0; ky < 4; ++ky) {
        int p = y + ky - 2;
        if (p < 0 || (p & 1) || (p >> 1) >= 96) continue;
        #pragma unroll
        for (int kx = 0; kx < 4; ++kx) {
            int q = x + kx - 2;
            if (q < 0 || (q & 1) || (q >> 1) >= 160) continue;
            double fv = (double)flow[((b * 2 + c) * 96 + (p >> 1)) * 160 + (q >> 1)];
            double wv = (double)up_w[c * 16 + (3 - ky) * 4 + (3 - kx)];
            double prod = fv * wv;
            acc = acc + prod;
        }
    }
    flow_up[idx] = acc;
}

// ---------------------------------------------------------------------------
// 2) warp: bilinear + oob mask, fp64 coords; OUTPUT = bf16-pair dwords
//    XCD-bijective swizzle (validated R5: -64us)
// ---------------------------------------------------------------------------
__global__ __launch_bounds__(256) void warp_kernel(
    const float* __restrict__ feats, const double* __restrict__ flow_up,
    uint* __restrict__ wp)
{
#pragma clang fp contract(off)
    int raw = blockIdx.x;                        // 0..1919
    int eb  = (raw & 7) * 240 + (raw >> 3);      // bijective (1920%8==0)
    int g = eb / 960;                            // channel-group 0/1
    int idx = (eb % 960) * 256 + threadIdx.x;    // over B*H*W
    int x = idx % W;
    int y = (idx / W) % H;
    int b = idx / HW_;

    double f0 = flow_up[(size_t)(b * 2 + 0) * HW_ + y * W + x];
    double f1 = flow_up[(size_t)(b * 2 + 1) * HW_ + y * W + x];

    double stepx = 2.0 / (double)(W - 1);
    double stepy = 2.0 / (double)(H - 1);
    double gx = (x == W - 1) ? 1.0 : ((double)x * stepx + (-1.0));
    double gy = (y == H - 1) ? 1.0 : ((double)y * stepy + (-1.0));
    double cxs = 2.0 * 2.5 / (double)(W - 1);
    double cys = 2.0 * 2.5 / (double)(H - 1);
    double sx = gx + f0 * cxs;
    double sy = gy + f1 * cys;
    double px = (sx + 1.0) * 0.5 * (double)(W - 1);
    double py = (sy + 1.0) * 0.5 * (double)(H - 1);

    double pxc = px < 0.0 ? 0.0 : (px > (double)(W - 1) ? (double)(W - 1) : px);
    double pyc = py < 0.0 ? 0.0 : (py > (double)(H - 1) ? (double)(H - 1) : py);
    double x0 = floor(pxc), y0 = floor(pyc);
    double tx = pxc - x0, ty = pyc - y0;
    int x0i = (int)x0, y0i = (int)y0;
    int y1i = min(y0i + 1, H - 1);

    double fx0 = floor(px), fy0 = floor(py);
    double mtx = px - fx0, mty = py - fy0;
    double w00 = (1.0 - mtx) * (1.0 - mty);
    double w01 = mtx * (1.0 - mty);
    double w10 = (1.0 - mtx) * mty;
    double w11 = mtx * mty;
    double m = 0.0;
    double xi, yi;
    xi = fx0;       yi = fy0;
    if (xi >= 0.0 && xi <= (double)(W - 1) && yi >= 0.0 && yi <= (double)(H - 1)) m = m + w00;
    xi = fx0 + 1.0; yi = fy0;
    if (xi >= 0.0 && xi <= (double)(W - 1) && yi >= 0.0 && yi <= (double)(H - 1)) m = m + w01;
    xi = fx0;       yi = fy0 + 1.0;
    if (xi >= 0.0 && xi <= (double)(W - 1) && yi >= 0.0 && yi <= (double)(H - 1)) m = m + w10;
    xi = fx0 + 1.0; yi = fy0 + 1.0;
    if (xi >= 0.0 && xi <= (double)(W - 1) && yi >= 0.0 && yi <= (double)(H - 1)) m = m + w11;
    float mask = (m >= 1.0) ? 1.0f : 0.0f;

    float a00 = (float)((1.0 - tx) * (1.0 - ty)) * mask;
    float a01 = (float)(tx * (1.0 - ty)) * mask;
    float a10 = (float)((1.0 - tx) * ty) * mask;
    float a11 = (float)(tx * ty) * mask;

    // rebase so the two x-corners are a contiguous float2
    int base = min(x0i, W - 2);
    bool xe = (x0i == W - 1);                 // only then does corner0 sit at .y
    int r0 = y0i * W + base;
    int r1 = y1i * W + base;

    const float* img = feats + (size_t)(b * 2 + 1) * C * HW_;
    uint* dst = wp + (size_t)b * 64 * HW_ + y * W + x;
    #pragma unroll 4
    for (int c2 = g * 32; c2 < g * 32 + 32; ++c2) {
        const float* p0 = img + (size_t)(2 * c2) * HW_;
        const float* p1 = p0 + HW_;
        float2 L0 = *(const float2*)&p0[r0];
        float2 L1 = *(const float2*)&p0[r1];
        float2 M0 = *(const float2*)&p1[r0];
        float2 M1 = *(const float2*)&p1[r1];
        float v00 = xe ? L0.y : L0.x;
        float v10 = xe ? L1.y : L1.x;
        float u00 = xe ? M0.y : M0.x;
        float u10 = xe ? M1.y : M1.x;
        float lo = a00 * v00 + a01 * L0.y + a10 * v10 + a11 * L1.y;
        float hi = a00 * u00 + a01 * M0.y + a10 * u10 + a11 * M1.y;
        dst[(size_t)c2 * HW_] = pack2bf(lo, hi);
    }
}

// ---------------------------------------------------------------------------
// 3) weight repack:  w -> [tap][coP][cinP] bf16, zero-padded
// ---------------------------------------------------------------------------
__global__ __launch_bounds__(256) void repack_w_kernel(
    const float* __restrict__ w1, const float* __restrict__ w2,
    const float* __restrict__ w3, const float* __restrict__ w4,
    unsigned short* __restrict__ wr)
{
    int idx = blockIdx.x * 256 + threadIdx.x;
    if (idx >= 178688) return;
    float v = 0.f;
    if (idx < 73728) {
        int tap = idx / 8192, r = idx % 8192, co = r / 64, ci = r % 64;
        if (ci < 49) v = w1[(co * 49 + ci) * 9 + tap];
    } else if (idx < 147456) {
        int i2 = idx - 73728;
        int tap = i2 / 8192, r = i2 % 8192, co = r / 128, ci = r % 128;
        v = w2[(co * 128 + ci) * 9 + tap];
    } else if (idx < 165888) {
        int i3 = idx - 147456;
        int tap = i3 / 2048, r = i3 % 2048, co = r / 64, ci = r % 64;
        v = w3[(co * 64 + ci) * 9 + tap];
    } else {
        int i4 = idx - 165888;
        int tap = i4 / 512, r = i4 % 512, co = r / 32, ci = r % 32;
        if (co < 2) v = w4[(co * 32 + ci) * 25 + tap];
    }
    wr[idx] = f2bf(v);
}

// ---------------------------------------------------------------------------
// 4) correlation via MFMA. R7: T14 register-prefetch pipeline — chunk ck+1's
//    global loads are ISSUED right after the post-commit barrier (in flight
//    during MFMAs + trailing barrier), COMMITTED to LDS after the barrier.
//    Same barrier count/LDS; +28 VGPR. Keeps R6 pads (SP=42, stage 65) +
//    XCD swizzle.
// ---------------------------------------------------------------------------
__global__ __launch_bounds__(256, 4) void corr_kernel(
    const float* __restrict__ feats, const uint* __restrict__ wp,
    uint* __restrict__ corrb)
{
    constexpr int SP = 42;                             // padded stride (halfs)
    __shared__ unsigned short lds[(320 + 64) * SP];    // 32256 B
    float* stage = (float*)lds;                        // 49 x 65 f32 epilogue

    int raw = blockIdx.x;
    int t = (raw & 7) * 480 + (raw >> 3);              // bijective (3840%8==0)
    int xt = t % 10, yg = (t / 10) % 96, b = t / 960;
    int x0 = xt * 32, y0 = yg * 2;
    int tid = threadIdx.x;
    int lane = tid & 63, wave = tid >> 6;
    int lanelo = lane & 15, laneq = (lane >> 4) & 3;
    int h = wave & 1, yr = wave >> 1;

    // per-lane window-tile addresses (halfs), hoisted out of the ck loop
    int baddr[10], di_t[10], c_t[10];
    #pragma unroll
    for (int tt = 0; tt < 10; ++tt) {
        int p = tt * 16 + lanelo;
        int di = p / 22, cc = p - di * 22;
        di_t[tt] = di; c_t[tt] = cc;
        int addr = ((yr + di) * 40 + h * 16 + cc + 1) * SP + laneq * 8;
        baddr[tt] = (di > 6) ? 0 : addr;
    }
    int qaddr = (320 + yr * 32 + h * 16 + lanelo) * SP + laneq * 8;

    f32x4 acc[10];
    #pragma unroll
    for (int tt = 0; tt < 10; ++tt) acc[tt] = f32x4{0.f, 0.f, 0.f, 0.f};

    const uint* wpb = wp + (size_t)b * 64 * HW_;
    const float* f1b = feats + (size_t)(b * 2) * C * HW_;

    uint4 pk[5];
    float q0v[4], q1v[4];

    auto issue = [&](int ck) {
        #pragma unroll
        for (int i = 0; i < 5; ++i) {
            int u = tid + i * 256;
            int q = u % 10, pp = (u / 10) & 15, r = u / 160;
            int gy = y0 - 3 + r, gx0 = x0 - 4 + 4 * q;
            uint4 v = {0, 0, 0, 0};
            if (gy >= 0 && gy < H && gx0 >= 0 && gx0 < W)
                v = *(const uint4*)&wpb[(size_t)(ck * 16 + pp) * HW_ + gy * W + gx0];
            pk[i] = v;
        }
        #pragma unroll
        for (int i = 0; i < 4; ++i) {
            int u = tid + i * 256;
            int px = u & 63, pp = u >> 6;
            int gx = x0 + (px & 31), gy = y0 + (px >> 5);
            const float* p0 = f1b + (size_t)(ck * 32 + 2 * pp) * HW_ + gy * W + gx;
            q0v[i] = p0[0];
            q1v[i] = p0[HW_];
        }
    };
    auto commit = [&]() {
        #pragma unroll
        for (int i = 0; i < 5; ++i) {
            int u = tid + i * 256;
            int q = u % 10, pp = (u / 10) & 15, r = u / 160;
            int pxb = (r * 40 + 4 * q) * SP + 2 * pp;
            *(uint*)&lds[pxb]          = pk[i].x;
            *(uint*)&lds[pxb + SP]     = pk[i].y;
            *(uint*)&lds[pxb + 2 * SP] = pk[i].z;
            *(uint*)&lds[pxb + 3 * SP] = pk[i].w;
        }
        #pragma unroll
        for (int i = 0; i < 4; ++i) {
            int u = tid + i * 256;
            int px = u & 63, pp = u >> 6;
            *(uint*)&lds[(320 + px) * SP + 2 * pp] = pack2bf(q0v[i], q1v[i]);
        }
    };

    issue(0);
    for (int ck = 0; ck < 4; ++ck) {
        commit();
        __syncthreads();
        if (ck < 3) issue(ck + 1);            // in flight across MFMAs+barrier
        const short8 qf = *(const short8*)&lds[qaddr];
        #pragma unroll
        for (int tt = 0; tt < 10; ++tt) {
            const short8 kf = *(const short8*)&lds[baddr[tt]];
            acc[tt] = __builtin_amdgcn_mfma_f32_16x16x32_bf16(qf, kf, acc[tt], 0, 0, 0);
        }
        __syncthreads();                      // reads done before next commit / scatter
    }
    // scatter the valid band entries: S[i, p] -> stage[di*7+dj][px] (65-pad)
    #pragma unroll
    for (int tt = 0; tt < 10; ++tt) {
        int di = di_t[tt];
        #pragma unroll
        for (int reg = 0; reg < 4; ++reg) {
            int i = laneq * 4 + reg;
            int dj = c_t[tt] - i;
            if (di <= 6 && dj >= 0 && dj < 7)
                stage[(di * 7 + dj) * 65 + yr * 32 + h * 16 + i] = acc[tt][reg];
        }
    }
    __syncthreads();
    // leaky + /128 + bf16 pair-pack + store
    uint* outp = corrb + (size_t)b * 32 * HW_;
    #pragma unroll
    for (int i = 0; i < 8; ++i) {
        int u = tid + i * 256;
        int px = u & 63, k2 = u >> 6;
        int gx = x0 + (px & 31), gy = y0 + (px >> 5);
        float v0 = (2 * k2 < 49) ? stage[(2 * k2) * 65 + px] : 0.f;
        float v1 = (2 * k2 + 1 < 49) ? stage[(2 * k2 + 1) * 65 + px] : 0.f;
        v0 = v0 > 0.f ? v0 : 0.1f * v0;
        v1 = v1 > 0.f ? v1 : 0.1f * v1;
        outp[(size_t)k2 * HW_ + gy * W + gx] = pack2bf(v0 * (1.f / 128.f), v1 * (1.f / 128.f));
    }
}

// ---------------------------------------------------------------------------
// 5) 3x3 conv, 32x32x16 MFMA. R7: T14 register-prefetch across cin-chunks
//    (R5 PMC: MfmaUtil 18 / VALU 16 / HBM 1.4TB/s -> pure latency exposure).
//    S2=21 pad + XCD swizzle kept from R6.
// ---------------------------------------------------------------------------
template<int CINP, int COUTP, int WCO, int WROWS, int MG, int NR, int MINW>
__global__ __launch_bounds__(256, MINW) void conv3x3_kernel(
    const uint* __restrict__ in, const unsigned short* __restrict__ wr,
    const float* __restrict__ bias, uint* __restrict__ outp, int cpx)
{
    constexpr int TH = WROWS * NR;
    constexpr int RH = TH + 2;
    constexpr int RW = 40, S2 = 21;
    constexpr int CHUNKS = CINP / 32;
    constexpr int UNITS = RH * 10 * 16;
    constexpr int NL = (UNITS + 255) / 256;
    __shared__ uint lds32[RH * RW * S2];

    int tid = threadIdx.x;
    int lane = tid & 63, wave = tid >> 6;
    int lane5 = lane & 31, kg = lane >> 5;
    int cow = (WCO == 1) ? 0 : (wave & 1);
    int rowg = (WCO == 1) ? wave : (wave >> 1);

    int raw = blockIdx.x;
    int bx = (raw & 7) * cpx + (raw >> 3);    // bijective XCD swizzle (grid%8==0)
    int xt = bx % 10;
    int yt = (bx / 10) % (H / TH);
    int b = bx / (10 * (H / TH));
    int tx0 = xt * 32, ty0 = yt * TH;
    int cob = cow * MG * 32;

    f32x16 acc[MG][NR];
    #pragma unroll
    for (int mg = 0; mg < MG; ++mg)
        #pragma unroll
        for (int nr = 0; nr < NR; ++nr)
            #pragma unroll
            for (int j = 0; j < 16; ++j) acc[mg][nr][j] = 0.f;

    const uint* inb = in + (size_t)b * (CINP / 2) * HW_;

    uint4 pre[NL];
    auto issue = [&](int ck) {
        #pragma unroll
        for (int i = 0; i < NL; ++i) {
            int s = tid + i * 256;
            uint4 v = {0, 0, 0, 0};
            if (s < UNITS) {
                int q = s % 10;
                int pp = (s / 10) % 16;
                int r = s / 160;
                int gy = ty0 - 1 + r;
                int gx0 = tx0 - 4 + 4 * q;
                if (gy >= 0 && gy < H && gx0 >= 0 && gx0 < W)
                    v = *(const uint4*)&inb[(size_t)(ck * 16 + pp) * HW_ + gy * W + gx0];
            }
            pre[i] = v;
        }
    };
    auto commit = [&]() {
        #pragma unroll
        for (int i = 0; i < NL; ++i) {
            int s = tid + i * 256;
            if (s < UNITS) {
                int q = s % 10;
                int pp = (s / 10) % 16;
                int r = s / 160;
                int pbase = (r * RW + 4 * q) * S2 + pp;
                lds32[pbase]          = pre[i].x;
                lds32[pbase + S2]     = pre[i].y;
                lds32[pbase + 2 * S2] = pre[i].z;
                lds32[pbase + 3 * S2] = pre[i].w;
            }
        }
    };

    issue(0);
    for (int ck = 0; ck < CHUNKS; ++ck) {
        commit();
        __syncthreads();
        if (ck + 1 < CHUNKS) issue(ck + 1);   // hides under taps/MFMA below

        for (int tap = 0; tap < 9; ++tap) {   // dynamic: keeps A-frag regs low
            int ky = tap / 3, kx = tap - ky * 3;
            short8 A[MG][2];
            #pragma unroll
            for (int mg = 0; mg < MG; ++mg)
                #pragma unroll
                for (int ks = 0; ks < 2; ++ks)
                    A[mg][ks] = *(const short8*)&wr[
                        ((size_t)tap * COUTP + cob + mg * 32 + lane5) * CINP +
                        ck * 32 + ks * 16 + kg * 8];
            #pragma unroll
            for (int nr = 0; nr < NR; ++nr) {
                int rr = rowg * NR + nr + ky;
                int col = lane5 + kx + 3;
                #pragma unroll
                for (int ks = 0; ks < 2; ++ks) {
                    const short8 Bf = *(const short8*)&lds32[(rr * RW + col) * S2 + ks * 8 + kg * 4];
                    #pragma unroll
                    for (int mg = 0; mg < MG; ++mg)
                        acc[mg][nr] = __builtin_amdgcn_mfma_f32_32x32x16_bf16(
                            A[mg][ks], Bf, acc[mg][nr], 0, 0, 0);
                }
            }
        }
        if (ck + 1 < CHUNKS) __syncthreads(); // reads done before next commit
    }

    // epilogue: C row = (reg&3) + 8*(reg>>2) + 4*kg; reg pairs -> even co pairs
    int xg = tx0 + lane5;
    #pragma unroll
    for (int mg = 0; mg < MG; ++mg)
        #pragma unroll
        for (int nr = 0; nr < NR; ++nr) {
            int ygl = ty0 + rowg * NR + nr;
            #pragma unroll
            for (int j = 0; j < 8; ++j) {
                int com = ((2 * j) & 3) + 8 * (j >> 1) + 4 * kg;
                int co = cob + mg * 32 + com;
                float v0 = acc[mg][nr][2 * j] + bias[co];
                float v1 = acc[mg][nr][2 * j + 1] + bias[co + 1];
                v0 = v0 > 0.f ? v0 : 0.1f * v0;
                v1 = v1 > 0.f ? v1 : 0.1f * v1;
                outp[((size_t)b * (COUTP / 2) + (co >> 1)) * HW_ + ygl * W + xg] =
                    pack2bf(v0, v1);
            }
        }
}

// ---------------------------------------------------------------------------
// 6) conv4 (5x5, cout 2 padded to 16, +bias +flow_up, fp32 out) — 16x16x32 MFMA
//    CHUNKS=1: no cross-chunk prefetch possible; unchanged from R6.
// ---------------------------------------------------------------------------
template<int CINP, int COUTP, int M_TILES, int N_TILES, int KS, int MINW>
__global__ __launch_bounds__(256, MINW) void conv_mfma_kernel(
    const uint* __restrict__ in, const unsigned short* __restrict__ wr,
    const float* __restrict__ bias, float* __restrict__ outp,
    const double* __restrict__ flow_up, int coutReal, int cpx)
{
    constexpr int CHUNK = 32;
    constexpr int PADK = KS / 2;
    constexpr int PX_GROUPS = 4 / M_TILES;
    constexpr int TH = PX_GROUPS * (N_TILES / 2);
    constexpr int RH = TH + KS - 1;
    constexpr int RW = 40;
    constexpr int S2 = 21;
    constexpr int CHUNKS = CINP / CHUNK;
    __shared__ uint lds32[RH * RW * S2];

    int tid = threadIdx.x;
    int lanelo = tid & 15, laneq = (tid >> 4) & 3, wave = tid >> 6;
    int m_idx = wave % M_TILES, pgroup = wave / M_TILES;
    int pg_row0 = pgroup * (N_TILES / 2);

    int raw = blockIdx.x;
    int bx = (raw & 7) * cpx + (raw >> 3);
    int xt = bx % 10;
    int yt = (bx / 10) % (H / TH);
    int b = bx / (10 * (H / TH));
    int tx0 = xt * 32, ty0 = yt * TH;
    int cob = m_idx * 16;

    f32x4 acc[N_TILES];
    #pragma unroll
    for (int n = 0; n < N_TILES; ++n) acc[n] = f32x4{0.f, 0.f, 0.f, 0.f};

    const uint* inb = in + (size_t)b * (CINP / 2) * HW_;

    for (int ck = 0; ck < CHUNKS; ++ck) {
        constexpr int UNITS = RH * (CHUNK / 2) * 10;
        for (int s = tid; s < UNITS; s += 256) {
            int q = s % 10;
            int pp = (s / 10) % (CHUNK / 2);
            int r = s / (10 * (CHUNK / 2));
            int gy = ty0 - PADK + r;
            int gx0 = tx0 - 4 + q * 4;
            uint4 v = {0, 0, 0, 0};
            if (gy >= 0 && gy < H && gx0 >= 0 && gx0 < W)
                v = *(const uint4*)&inb[(size_t)(ck * (CHUNK / 2) + pp) * HW_ + gy * W + gx0];
            int pbase = (r * RW + q * 4) * S2 + pp;
            lds32[pbase] = v.x;
            lds32[pbase + S2] = v.y;
            lds32[pbase + 2 * S2] = v.z;
            lds32[pbase + 3 * S2] = v.w;
        }
        __syncthreads();

        short8 afr[KS * KS];
        #pragma unroll
        for (int tap = 0; tap < KS * KS; ++tap)
            afr[tap] = *(const short8*)&wr[
                ((size_t)tap * COUTP + cob + lanelo) * CINP + ck * CHUNK + laneq * 8];

        for (int tap = 0; tap < KS * KS; ++tap) {
            int ky = tap / KS, kx = tap - ky * KS;
            #pragma unroll
            for (int n = 0; n < N_TILES; ++n) {
                int rr = pg_row0 + (n >> 1) + ky;
                int pxi = (n & 1) * 16 + lanelo + (4 - PADK) + kx;
                const short8 bf = *(const short8*)&lds32[(rr * RW + pxi) * S2 + laneq * 4];
                acc[n] = __builtin_amdgcn_mfma_f32_16x16x32_bf16(afr[tap], bf, acc[n], 0, 0, 0);
            }
        }
        __syncthreads();
    }

    #pragma unroll
    for (int n = 0; n < N_TILES; ++n) {
        int x = tx0 + (n & 1) * 16 + lanelo;
        int y = ty0 + pg_row0 + (n >> 1);
        #pragma unroll
        for (int j = 0; j < 4; ++j) {
            int co = cob + laneq * 4 + j;
            if (co < coutReal) {
                float v = acc[n][j] + bias[co];
                v += (float)flow_up[((size_t)(b * 2) + co) * HW_ + y * W + x];
                outp[((size_t)b * coutReal + co) * HW_ + y * W + x] = v;
            }
        }
    }
}

// ---------------------------------------------------------------------------
extern "C" void kernel_launch(void* const* d_in, const int* in_sizes, int n_in,
                              void* d_out, int out_size, void* d_ws, size_t ws_size,
                              hipStream_t stream)
{
    const float* feats = (const float*)d_in[0];
    const float* flow  = (const float*)d_in[1];
    const float* up_w  = (const float*)d_in[2];
    const float* w1 = (const float*)d_in[3];
    const float* b1 = (const float*)d_in[4];
    const float* w2 = (const float*)d_in[5];
    const float* b2 = (const float*)d_in[6];
    const float* w3 = (const float*)d_in[7];
    const float* b3 = (const float*)d_in[8];
    const float* w4 = (const float*)d_in[9];
    const float* b4 = (const float*)d_in[10];
    float* out = (float*)d_out;

    char* ws = (char*)d_ws;
    double* flow_up = (double*)ws;                    // 3,932,160 B
    uint* wp    = (uint*)(ws + 3932160);              // warped bf16-pairs / h1
    uint* h1    = (uint*)(ws + 3932160);
    uint* corrb = (uint*)(ws + 66846720);             // corr / h2
    uint* h2    = corrb;
    uint* h3    = (uint*)(ws + 98304000);
    unsigned short* wr = (unsigned short*)(ws + 114032640);
    unsigned short* wr1 = wr;
    unsigned short* wr2 = wr + 73728;
    unsigned short* wr3 = wr + 147456;
    unsigned short* wr4 = wr + 165888;

    repack_w_kernel<<<699, 256, 0, stream>>>(w1, w2, w3, w4, wr);
    upflow_kernel<<<(B * 2 * HW_ + 255) / 256, 256, 0, stream>>>(flow, up_w, flow_up);
    warp_kernel<<<1920, 256, 0, stream>>>(feats, flow_up, wp);
    corr_kernel<<<3840, 256, 0, stream>>>(feats, wp, corrb);

    // conv1: cin 64(pad49) -> cout 128. grid 1920 -> cpx 240
    conv3x3_kernel<64, 128, 2, 2, 2, 2, 3>
        <<<1920, 256, 0, stream>>>(corrb, wr1, b1, h1, 240);
    // conv2: cin 128 -> cout 64. grid 960 -> cpx 120
    conv3x3_kernel<128, 64, 1, 4, 2, 2, 3>
        <<<960, 256, 0, stream>>>(h1, wr2, b2, h2, 120);
    // conv3: cin 64 -> cout 32. grid 960 -> cpx 120
    conv3x3_kernel<64, 32, 1, 4, 1, 2, 3>
        <<<960, 256, 0, stream>>>(h2, wr3, b3, h3, 120);
    // conv4: cin 32 -> cout 2 (pad 16), 5x5, fp32 out + bias + flow_up
    conv_mfma_kernel<32, 16, 1, 2, 5, 2>
        <<<1920, 256, 0, stream>>>(h3, wr4, b4, out, flow_up, 2, 240);
}

// Round 8
// 708.913 us; speedup vs baseline: 1.0792x; 1.0792x over previous
//
#include <hip/hip_runtime.h>

typedef __attribute__((ext_vector_type(8))) short short8;
typedef __attribute__((ext_vector_type(4))) float f32x4;
typedef __attribute__((ext_vector_type(16))) float f32x16;
typedef unsigned int uint;

constexpr int B = 4, C = 128, H = 192, W = 320;
constexpr int HW_ = H * W;

__device__ __forceinline__ unsigned short f2bf(float x) {
    uint u = __float_as_uint(x);
    u += 0x7fffu + ((u >> 16) & 1u);
    return (unsigned short)(u >> 16);
}
__device__ __forceinline__ uint pack2bf(float a, float b) {
    return (uint)f2bf(a) | ((uint)f2bf(b) << 16);
}

// ---------------------------------------------------------------------------
// 1) up_flow in fp64 (feeds floor()/mask decisions downstream)
// ---------------------------------------------------------------------------
__global__ __launch_bounds__(256) void upflow_kernel(
    const float* __restrict__ flow, const float* __restrict__ up_w,
    double* __restrict__ flow_up)
{
#pragma clang fp contract(off)
    int idx = blockIdx.x * 256 + threadIdx.x;
    if (idx >= B * 2 * HW_) return;
    int x = idx % W;
    int y = (idx / W) % H;
    int c = (idx / HW_) % 2;
    int b = idx / (2 * HW_);
    double acc = 0.0;
    #pragma unroll
    for (int ky = 0; ky < 4; ++ky) {
        int p = y + ky - 2;
        if (p < 0 || (p & 1) || (p >> 1) >= 96) continue;
        #pragma unroll
        for (int kx = 0; kx < 4; ++kx) {
            int q = x + kx - 2;
            if (q < 0 || (q & 1) || (q >> 1) >= 160) continue;
            double fv = (double)flow[((b * 2 + c) * 96 + (p >> 1)) * 160 + (q >> 1)];
            double wv = (double)up_w[c * 16 + (3 - ky) * 4 + (3 - kx)];
            double prod = fv * wv;
            acc = acc + prod;
        }
    }
    flow_up[idx] = acc;
}

// ---------------------------------------------------------------------------
// 2) warp: bilinear + oob mask, fp64 coords; OUTPUT = bf16-pair dwords
//    XCD-bijective swizzle (validated R5: -64us)
// ---------------------------------------------------------------------------
__global__ __launch_bounds__(256) void warp_kernel(
    const float* __restrict__ feats, const double* __restrict__ flow_up,
    uint* __restrict__ wp)
{
#pragma clang fp contract(off)
    int raw = blockIdx.x;                        // 0..1919
    int eb  = (raw & 7) * 240 + (raw >> 3);      // bijective (1920%8==0)
    int g = eb / 960;                            // channel-group 0/1
    int idx = (eb % 960) * 256 + threadIdx.x;    // over B*H*W
    int x = idx % W;
    int y = (idx / W) % H;
    int b = idx / HW_;

    double f0 = flow_up[(size_t)(b * 2 + 0) * HW_ + y * W + x];
    double f1 = flow_up[(size_t)(b * 2 + 1) * HW_ + y * W + x];

    double stepx = 2.0 / (double)(W - 1);
    double stepy = 2.0 / (double)(H - 1);
    double gx = (x == W - 1) ? 1.0 : ((double)x * stepx + (-1.0));
    double gy = (y == H - 1) ? 1.0 : ((double)y * stepy + (-1.0));
    double cxs = 2.0 * 2.5 / (double)(W - 1);
    double cys = 2.0 * 2.5 / (double)(H - 1);
    double sx = gx + f0 * cxs;
    double sy = gy + f1 * cys;
    double px = (sx + 1.0) * 0.5 * (double)(W - 1);
    double py = (sy + 1.0) * 0.5 * (double)(H - 1);

    double pxc = px < 0.0 ? 0.0 : (px > (double)(W - 1) ? (double)(W - 1) : px);
    double pyc = py < 0.0 ? 0.0 : (py > (double)(H - 1) ? (double)(H - 1) : py);
    double x0 = floor(pxc), y0 = floor(pyc);
    double tx = pxc - x0, ty = pyc - y0;
    int x0i = (int)x0, y0i = (int)y0;
    int y1i = min(y0i + 1, H - 1);

    double fx0 = floor(px), fy0 = floor(py);
    double mtx = px - fx0, mty = py - fy0;
    double w00 = (1.0 - mtx) * (1.0 - mty);
    double w01 = mtx * (1.0 - mty);
    double w10 = (1.0 - mtx) * mty;
    double w11 = mtx * mty;
    double m = 0.0;
    double xi, yi;
    xi = fx0;       yi = fy0;
    if (xi >= 0.0 && xi <= (double)(W - 1) && yi >= 0.0 && yi <= (double)(H - 1)) m = m + w00;
    xi = fx0 + 1.0; yi = fy0;
    if (xi >= 0.0 && xi <= (double)(W - 1) && yi >= 0.0 && yi <= (double)(H - 1)) m = m + w01;
    xi = fx0;       yi = fy0 + 1.0;
    if (xi >= 0.0 && xi <= (double)(W - 1) && yi >= 0.0 && yi <= (double)(H - 1)) m = m + w10;
    xi = fx0 + 1.0; yi = fy0 + 1.0;
    if (xi >= 0.0 && xi <= (double)(W - 1) && yi >= 0.0 && yi <= (double)(H - 1)) m = m + w11;
    float mask = (m >= 1.0) ? 1.0f : 0.0f;

    float a00 = (float)((1.0 - tx) * (1.0 - ty)) * mask;
    float a01 = (float)(tx * (1.0 - ty)) * mask;
    float a10 = (float)((1.0 - tx) * ty) * mask;
    float a11 = (float)(tx * ty) * mask;

    // rebase so the two x-corners are a contiguous float2
    int base = min(x0i, W - 2);
    bool xe = (x0i == W - 1);                 // only then does corner0 sit at .y
    int r0 = y0i * W + base;
    int r1 = y1i * W + base;

    const float* img = feats + (size_t)(b * 2 + 1) * C * HW_;
    uint* dst = wp + (size_t)b * 64 * HW_ + y * W + x;
    #pragma unroll 4
    for (int c2 = g * 32; c2 < g * 32 + 32; ++c2) {
        const float* p0 = img + (size_t)(2 * c2) * HW_;
        const float* p1 = p0 + HW_;
        float2 L0 = *(const float2*)&p0[r0];
        float2 L1 = *(const float2*)&p0[r1];
        float2 M0 = *(const float2*)&p1[r0];
        float2 M1 = *(const float2*)&p1[r1];
        float v00 = xe ? L0.y : L0.x;
        float v10 = xe ? L1.y : L1.x;
        float u00 = xe ? M0.y : M0.x;
        float u10 = xe ? M1.y : M1.x;
        float lo = a00 * v00 + a01 * L0.y + a10 * v10 + a11 * L1.y;
        float hi = a00 * u00 + a01 * M0.y + a10 * u10 + a11 * M1.y;
        dst[(size_t)c2 * HW_] = pack2bf(lo, hi);
    }
}

// ---------------------------------------------------------------------------
// 3) weight repack:  w -> [tap][coP][cinP] bf16, zero-padded
// ---------------------------------------------------------------------------
__global__ __launch_bounds__(256) void repack_w_kernel(
    const float* __restrict__ w1, const float* __restrict__ w2,
    const float* __restrict__ w3, const float* __restrict__ w4,
    unsigned short* __restrict__ wr)
{
    int idx = blockIdx.x * 256 + threadIdx.x;
    if (idx >= 178688) return;
    float v = 0.f;
    if (idx < 73728) {
        int tap = idx / 8192, r = idx % 8192, co = r / 64, ci = r % 64;
        if (ci < 49) v = w1[(co * 49 + ci) * 9 + tap];
    } else if (idx < 147456) {
        int i2 = idx - 73728;
        int tap = i2 / 8192, r = i2 % 8192, co = r / 128, ci = r % 128;
        v = w2[(co * 128 + ci) * 9 + tap];
    } else if (idx < 165888) {
        int i3 = idx - 147456;
        int tap = i3 / 2048, r = i3 % 2048, co = r / 64, ci = r % 64;
        v = w3[(co * 64 + ci) * 9 + tap];
    } else {
        int i4 = idx - 165888;
        int tap = i4 / 512, r = i4 % 512, co = r / 32, ci = r % 32;
        if (co < 2) v = w4[(co * 32 + ci) * 25 + tap];
    }
    wr[idx] = f2bf(v);
}

// ---------------------------------------------------------------------------
// 4) correlation via MFMA — exact R6 version (R7 prefetch reverted: compiler
//    drains vmcnt at barriers, prefetch regressed +60us). SP=42 pad,
//    stage 65 pad, XCD swizzle.
// ---------------------------------------------------------------------------
__global__ __launch_bounds__(256, 4) void corr_kernel(
    const float* __restrict__ feats, const uint* __restrict__ wp,
    uint* __restrict__ corrb)
{
    constexpr int SP = 42;                             // padded stride (halfs)
    __shared__ unsigned short lds[(320 + 64) * SP];    // 32256 B
    float* stage = (float*)lds;                        // 49 x 65 f32 epilogue

    int raw = blockIdx.x;
    int t = (raw & 7) * 480 + (raw >> 3);              // bijective (3840%8==0)
    int xt = t % 10, yg = (t / 10) % 96, b = t / 960;
    int x0 = xt * 32, y0 = yg * 2;
    int tid = threadIdx.x;
    int lane = tid & 63, wave = tid >> 6;
    int lanelo = lane & 15, laneq = (lane >> 4) & 3;
    int h = wave & 1, yr = wave >> 1;

    // per-lane window-tile addresses (halfs), hoisted out of the ck loop
    int baddr[10], di_t[10], c_t[10];
    #pragma unroll
    for (int tt = 0; tt < 10; ++tt) {
        int p = tt * 16 + lanelo;
        int di = p / 22, cc = p - di * 22;
        di_t[tt] = di; c_t[tt] = cc;
        int addr = ((yr + di) * 40 + h * 16 + cc + 1) * SP + laneq * 8;
        baddr[tt] = (di > 6) ? 0 : addr;
    }
    int qaddr = (320 + yr * 32 + h * 16 + lanelo) * SP + laneq * 8;

    f32x4 acc[10];
    #pragma unroll
    for (int tt = 0; tt < 10; ++tt) acc[tt] = f32x4{0.f, 0.f, 0.f, 0.f};

    const uint* wpb = wp + (size_t)b * 64 * HW_;
    const float* f1b = feats + (size_t)(b * 2) * C * HW_;

    for (int ck = 0; ck < 4; ++ck) {
        if (ck) __syncthreads();
        // stage K chunk: 8 rows x 10 quads x 16 pairs
        #pragma unroll
        for (int i = 0; i < 5; ++i) {
            int u = tid + i * 256;
            int q = u % 10, pp = (u / 10) & 15, r = u / 160;
            int gy = y0 - 3 + r, gx0 = x0 - 4 + 4 * q;
            uint4 v = {0, 0, 0, 0};
            if (gy >= 0 && gy < H && gx0 >= 0 && gx0 < W)
                v = *(const uint4*)&wpb[(size_t)(ck * 16 + pp) * HW_ + gy * W + gx0];
            int pxb = (r * 40 + 4 * q) * SP + 2 * pp;
            *(uint*)&lds[pxb]          = v.x;
            *(uint*)&lds[pxb + SP]     = v.y;
            *(uint*)&lds[pxb + 2 * SP] = v.z;
            *(uint*)&lds[pxb + 3 * SP] = v.w;
        }
        // stage Q chunk: 64 px x 16 pairs, fp32 -> bf16
        #pragma unroll
        for (int i = 0; i < 4; ++i) {
            int u = tid + i * 256;
            int px = u & 63, pp = u >> 6;
            int gx = x0 + (px & 31), gy = y0 + (px >> 5);
            const float* p0 = f1b + (size_t)(ck * 32 + 2 * pp) * HW_ + gy * W + gx;
            *(uint*)&lds[(320 + px) * SP + 2 * pp] = pack2bf(p0[0], p0[HW_]);
        }
        __syncthreads();
        const short8 qf = *(const short8*)&lds[qaddr];
        #pragma unroll
        for (int tt = 0; tt < 10; ++tt) {
            const short8 kf = *(const short8*)&lds[baddr[tt]];
            acc[tt] = __builtin_amdgcn_mfma_f32_16x16x32_bf16(qf, kf, acc[tt], 0, 0, 0);
        }
    }
    __syncthreads();
    // scatter the valid band entries: S[i, p] -> stage[di*7+dj][px] (65-pad)
    #pragma unroll
    for (int tt = 0; tt < 10; ++tt) {
        int di = di_t[tt];
        #pragma unroll
        for (int reg = 0; reg < 4; ++reg) {
            int i = laneq * 4 + reg;
            int dj = c_t[tt] - i;
            if (di <= 6 && dj >= 0 && dj < 7)
                stage[(di * 7 + dj) * 65 + yr * 32 + h * 16 + i] = acc[tt][reg];
        }
    }
    __syncthreads();
    // leaky + /128 + bf16 pair-pack + store
    uint* outp = corrb + (size_t)b * 32 * HW_;
    #pragma unroll
    for (int i = 0; i < 8; ++i) {
        int u = tid + i * 256;
        int px = u & 63, k2 = u >> 6;
        int gx = x0 + (px & 31), gy = y0 + (px >> 5);
        float v0 = (2 * k2 < 49) ? stage[(2 * k2) * 65 + px] : 0.f;
        float v1 = (2 * k2 + 1 < 49) ? stage[(2 * k2 + 1) * 65 + px] : 0.f;
        v0 = v0 > 0.f ? v0 : 0.1f * v0;
        v1 = v1 > 0.f ? v1 : 0.1f * v1;
        outp[(size_t)k2 * HW_ + gy * W + gx] = pack2bf(v0 * (1.f / 128.f), v1 * (1.f / 128.f));
    }
}

// ---------------------------------------------------------------------------
// 5) 3x3 conv, 32x32x16 MFMA. R8: block size parametrized (NT threads);
//    conv1/conv2 move to 128-thread blocks with half the y-tile -> 2x grid,
//    ~2x resident blocks/CU (TLP hides the serial stage->barrier->MFMA
//    latency that R5 PMC showed: all pipes <35% duty). S2=21 pad + XCD
//    swizzle kept. R7 reg-prefetch reverted (regressed).
// ---------------------------------------------------------------------------
template<int CINP, int COUTP, int WCO, int WROWS, int MG, int NR, int MINW>
__global__ __launch_bounds__(WCO * WROWS * 64, MINW) void conv3x3_kernel(
    const uint* __restrict__ in, const unsigned short* __restrict__ wr,
    const float* __restrict__ bias, uint* __restrict__ outp, int cpx)
{
    constexpr int NT = WCO * WROWS * 64;
    constexpr int TH = WROWS * NR;
    constexpr int RH = TH + 2;
    constexpr int RW = 40, S2 = 21;
    constexpr int CHUNKS = CINP / 32;
    __shared__ uint lds32[RH * RW * S2];

    int tid = threadIdx.x;
    int lane = tid & 63, wave = tid >> 6;
    int lane5 = lane & 31, kg = lane >> 5;
    int cow = (WCO == 1) ? 0 : (wave & 1);
    int rowg = (WCO == 1) ? wave : (wave >> 1);

    int raw = blockIdx.x;
    int bx = (raw & 7) * cpx + (raw >> 3);    // bijective XCD swizzle (grid%8==0)
    int xt = bx % 10;
    int yt = (bx / 10) % (H / TH);
    int b = bx / (10 * (H / TH));
    int tx0 = xt * 32, ty0 = yt * TH;
    int cob = cow * MG * 32;

    f32x16 acc[MG][NR];
    #pragma unroll
    for (int mg = 0; mg < MG; ++mg)
        #pragma unroll
        for (int nr = 0; nr < NR; ++nr)
            #pragma unroll
            for (int j = 0; j < 16; ++j) acc[mg][nr][j] = 0.f;

    const uint* inb = in + (size_t)b * (CINP / 2) * HW_;

    for (int ck = 0; ck < CHUNKS; ++ck) {
        if (ck) __syncthreads();
        constexpr int UNITS = RH * 10 * 16;
        for (int s = tid; s < UNITS; s += NT) {
            int q = s % 10;
            int pp = (s / 10) % 16;
            int r = s / 160;
            int gy = ty0 - 1 + r;
            int gx0 = tx0 - 4 + 4 * q;
            uint4 v = {0, 0, 0, 0};
            if (gy >= 0 && gy < H && gx0 >= 0 && gx0 < W)
                v = *(const uint4*)&inb[(size_t)(ck * 16 + pp) * HW_ + gy * W + gx0];
            int pbase = (r * RW + 4 * q) * S2 + pp;
            lds32[pbase]          = v.x;
            lds32[pbase + S2]     = v.y;
            lds32[pbase + 2 * S2] = v.z;
            lds32[pbase + 3 * S2] = v.w;
        }
        __syncthreads();

        for (int tap = 0; tap < 9; ++tap) {   // dynamic: keeps A-frag regs low
            int ky = tap / 3, kx = tap - ky * 3;
            short8 A[MG][2];
            #pragma unroll
            for (int mg = 0; mg < MG; ++mg)
                #pragma unroll
                for (int ks = 0; ks < 2; ++ks)
                    A[mg][ks] = *(const short8*)&wr[
                        ((size_t)tap * COUTP + cob + mg * 32 + lane5) * CINP +
                        ck * 32 + ks * 16 + kg * 8];
            #pragma unroll
            for (int nr = 0; nr < NR; ++nr) {
                int rr = rowg * NR + nr + ky;
                int col = lane5 + kx + 3;
                #pragma unroll
                for (int ks = 0; ks < 2; ++ks) {
                    const short8 Bf = *(const short8*)&lds32[(rr * RW + col) * S2 + ks * 8 + kg * 4];
                    #pragma unroll
                    for (int mg = 0; mg < MG; ++mg)
                        acc[mg][nr] = __builtin_amdgcn_mfma_f32_32x32x16_bf16(
                            A[mg][ks], Bf, acc[mg][nr], 0, 0, 0);
                }
            }
        }
    }

    // epilogue: C row = (reg&3) + 8*(reg>>2) + 4*kg; reg pairs -> even co pairs
    int xg = tx0 + lane5;
    #pragma unroll
    for (int mg = 0; mg < MG; ++mg)
        #pragma unroll
        for (int nr = 0; nr < NR; ++nr) {
            int ygl = ty0 + rowg * NR + nr;
            #pragma unroll
            for (int j = 0; j < 8; ++j) {
                int com = ((2 * j) & 3) + 8 * (j >> 1) + 4 * kg;
                int co = cob + mg * 32 + com;
                float v0 = acc[mg][nr][2 * j] + bias[co];
                float v1 = acc[mg][nr][2 * j + 1] + bias[co + 1];
                v0 = v0 > 0.f ? v0 : 0.1f * v0;
                v1 = v1 > 0.f ? v1 : 0.1f * v1;
                outp[((size_t)b * (COUTP / 2) + (co >> 1)) * HW_ + ygl * W + xg] =
                    pack2bf(v0, v1);
            }
        }
}

// ---------------------------------------------------------------------------
// 6) conv4 (5x5, cout 2 padded to 16, +bias +flow_up, fp32 out) — 16x16x32 MFMA
//    unchanged from R6 (CHUNKS=1).
// ---------------------------------------------------------------------------
template<int CINP, int COUTP, int M_TILES, int N_TILES, int KS, int MINW>
__global__ __launch_bounds__(256, MINW) void conv_mfma_kernel(
    const uint* __restrict__ in, const unsigned short* __restrict__ wr,
    const float* __restrict__ bias, float* __restrict__ outp,
    const double* __restrict__ flow_up, int coutReal, int cpx)
{
    constexpr int CHUNK = 32;
    constexpr int PADK = KS / 2;
    constexpr int PX_GROUPS = 4 / M_TILES;
    constexpr int TH = PX_GROUPS * (N_TILES / 2);
    constexpr int RH = TH + KS - 1;
    constexpr int RW = 40;
    constexpr int S2 = 21;
    constexpr int CHUNKS = CINP / CHUNK;
    __shared__ uint lds32[RH * RW * S2];

    int tid = threadIdx.x;
    int lanelo = tid & 15, laneq = (tid >> 4) & 3, wave = tid >> 6;
    int m_idx = wave % M_TILES, pgroup = wave / M_TILES;
    int pg_row0 = pgroup * (N_TILES / 2);

    int raw = blockIdx.x;
    int bx = (raw & 7) * cpx + (raw >> 3);
    int xt = bx % 10;
    int yt = (bx / 10) % (H / TH);
    int b = bx / (10 * (H / TH));
    int tx0 = xt * 32, ty0 = yt * TH;
    int cob = m_idx * 16;

    f32x4 acc[N_TILES];
    #pragma unroll
    for (int n = 0; n < N_TILES; ++n) acc[n] = f32x4{0.f, 0.f, 0.f, 0.f};

    const uint* inb = in + (size_t)b * (CINP / 2) * HW_;

    for (int ck = 0; ck < CHUNKS; ++ck) {
        constexpr int UNITS = RH * (CHUNK / 2) * 10;
        for (int s = tid; s < UNITS; s += 256) {
            int q = s % 10;
            int pp = (s / 10) % (CHUNK / 2);
            int r = s / (10 * (CHUNK / 2));
            int gy = ty0 - PADK + r;
            int gx0 = tx0 - 4 + q * 4;
            uint4 v = {0, 0, 0, 0};
            if (gy >= 0 && gy < H && gx0 >= 0 && gx0 < W)
                v = *(const uint4*)&inb[(size_t)(ck * (CHUNK / 2) + pp) * HW_ + gy * W + gx0];
            int pbase = (r * RW + q * 4) * S2 + pp;
            lds32[pbase] = v.x;
            lds32[pbase + S2] = v.y;
            lds32[pbase + 2 * S2] = v.z;
            lds32[pbase + 3 * S2] = v.w;
        }
        __syncthreads();

        short8 afr[KS * KS];
        #pragma unroll
        for (int tap = 0; tap < KS * KS; ++tap)
            afr[tap] = *(const short8*)&wr[
                ((size_t)tap * COUTP + cob + lanelo) * CINP + ck * CHUNK + laneq * 8];

        for (int tap = 0; tap < KS * KS; ++tap) {
            int ky = tap / KS, kx = tap - ky * KS;
            #pragma unroll
            for (int n = 0; n < N_TILES; ++n) {
                int rr = pg_row0 + (n >> 1) + ky;
                int pxi = (n & 1) * 16 + lanelo + (4 - PADK) + kx;
                const short8 bf = *(const short8*)&lds32[(rr * RW + pxi) * S2 + laneq * 4];
                acc[n] = __builtin_amdgcn_mfma_f32_16x16x32_bf16(afr[tap], bf, acc[n], 0, 0, 0);
            }
        }
        __syncthreads();
    }

    #pragma unroll
    for (int n = 0; n < N_TILES; ++n) {
        int x = tx0 + (n & 1) * 16 + lanelo;
        int y = ty0 + pg_row0 + (n >> 1);
        #pragma unroll
        for (int j = 0; j < 4; ++j) {
            int co = cob + laneq * 4 + j;
            if (co < coutReal) {
                float v = acc[n][j] + bias[co];
                v += (float)flow_up[((size_t)(b * 2) + co) * HW_ + y * W + x];
                outp[((size_t)b * coutReal + co) * HW_ + y * W + x] = v;
            }
        }
    }
}

// ---------------------------------------------------------------------------
extern "C" void kernel_launch(void* const* d_in, const int* in_sizes, int n_in,
                              void* d_out, int out_size, void* d_ws, size_t ws_size,
                              hipStream_t stream)
{
    const float* feats = (const float*)d_in[0];
    const float* flow  = (const float*)d_in[1];
    const float* up_w  = (const float*)d_in[2];
    const float* w1 = (const float*)d_in[3];
    const float* b1 = (const float*)d_in[4];
    const float* w2 = (const float*)d_in[5];
    const float* b2 = (const float*)d_in[6];
    const float* w3 = (const float*)d_in[7];
    const float* b3 = (const float*)d_in[8];
    const float* w4 = (const float*)d_in[9];
    const float* b4 = (const float*)d_in[10];
    float* out = (float*)d_out;

    char* ws = (char*)d_ws;
    double* flow_up = (double*)ws;                    // 3,932,160 B
    uint* wp    = (uint*)(ws + 3932160);              // warped bf16-pairs / h1
    uint* h1    = (uint*)(ws + 3932160);
    uint* corrb = (uint*)(ws + 66846720);             // corr / h2
    uint* h2    = corrb;
    uint* h3    = (uint*)(ws + 98304000);
    unsigned short* wr = (unsigned short*)(ws + 114032640);
    unsigned short* wr1 = wr;
    unsigned short* wr2 = wr + 73728;
    unsigned short* wr3 = wr + 147456;
    unsigned short* wr4 = wr + 165888;

    repack_w_kernel<<<699, 256, 0, stream>>>(w1, w2, w3, w4, wr);
    upflow_kernel<<<(B * 2 * HW_ + 255) / 256, 256, 0, stream>>>(flow, up_w, flow_up);
    warp_kernel<<<1920, 256, 0, stream>>>(feats, flow_up, wp);
    corr_kernel<<<3840, 256, 0, stream>>>(feats, wp, corrb);

    // conv1: cin 64(pad49) -> cout 128. 128-thr blocks, TH=2, grid 3840 (cpx 480)
    conv3x3_kernel<64, 128, 2, 1, 2, 2, 3>
        <<<3840, 128, 0, stream>>>(corrb, wr1, b1, h1, 480);
    // conv2: cin 128 -> cout 64. 128-thr blocks, TH=4, grid 1920 (cpx 240)
    conv3x3_kernel<128, 64, 1, 2, 2, 2, 3>
        <<<1920, 128, 0, stream>>>(h1, wr2, b2, h2, 240);
    // conv3: cin 64 -> cout 32. unchanged (256 thr, TH=8, grid 960, cpx 120)
    conv3x3_kernel<64, 32, 1, 4, 1, 2, 3>
        <<<960, 256, 0, stream>>>(h2, wr3, b3, h3, 120);
    // conv4: cin 32 -> cout 2 (pad 16), 5x5, fp32 out + bias + flow_up
    conv_mfma_kernel<32, 16, 1, 2, 5, 2>
        <<<1920, 256, 0, stream>>>(h3, wr4, b4, out, flow_up, 2, 240);
}

// Round 9
// 703.445 us; speedup vs baseline: 1.0876x; 1.0078x over previous
//
#include <hip/hip_runtime.h>

typedef __attribute__((ext_vector_type(8))) short short8;
typedef __attribute__((ext_vector_type(4))) float f32x4;
typedef __attribute__((ext_vector_type(16))) float f32x16;
typedef unsigned int uint;

constexpr int B = 4, C = 128, H = 192, W = 320;
constexpr int HW_ = H * W;

__device__ __forceinline__ unsigned short f2bf(float x) {
    uint u = __float_as_uint(x);
    u += 0x7fffu + ((u >> 16) & 1u);
    return (unsigned short)(u >> 16);
}
__device__ __forceinline__ uint pack2bf(float a, float b) {
    return (uint)f2bf(a) | ((uint)f2bf(b) << 16);
}

// ---------------------------------------------------------------------------
// 1) fused pre-pass: blocks [0,1920) = up_flow in fp64; blocks [1920,2619) =
//    weight repack. Independent outputs; merged to save one launch/drain gap.
// ---------------------------------------------------------------------------
__global__ __launch_bounds__(256) void prepass_kernel(
    const float* __restrict__ flow, const float* __restrict__ up_w,
    double* __restrict__ flow_up,
    const float* __restrict__ w1, const float* __restrict__ w2,
    const float* __restrict__ w3, const float* __restrict__ w4,
    unsigned short* __restrict__ wr)
{
#pragma clang fp contract(off)
    if (blockIdx.x < 1920) {
        int idx = blockIdx.x * 256 + threadIdx.x;
        int x = idx % W;
        int y = (idx / W) % H;
        int c = (idx / HW_) % 2;
        int b = idx / (2 * HW_);
        double acc = 0.0;
        #pragma unroll
        for (int ky = 0; ky < 4; ++ky) {
            int p = y + ky - 2;
            if (p < 0 || (p & 1) || (p >> 1) >= 96) continue;
            #pragma unroll
            for (int kx = 0; kx < 4; ++kx) {
                int q = x + kx - 2;
                if (q < 0 || (q & 1) || (q >> 1) >= 160) continue;
                double fv = (double)flow[((b * 2 + c) * 96 + (p >> 1)) * 160 + (q >> 1)];
                double wv = (double)up_w[c * 16 + (3 - ky) * 4 + (3 - kx)];
                double prod = fv * wv;
                acc = acc + prod;
            }
        }
        flow_up[idx] = acc;
    } else {
        int idx = (blockIdx.x - 1920) * 256 + threadIdx.x;
        if (idx >= 178688) return;
        float v = 0.f;
        if (idx < 73728) {
            int tap = idx / 8192, r = idx % 8192, co = r / 64, ci = r % 64;
            if (ci < 49) v = w1[(co * 49 + ci) * 9 + tap];
        } else if (idx < 147456) {
            int i2 = idx - 73728;
            int tap = i2 / 8192, r = i2 % 8192, co = r / 128, ci = r % 128;
            v = w2[(co * 128 + ci) * 9 + tap];
        } else if (idx < 165888) {
            int i3 = idx - 147456;
            int tap = i3 / 2048, r = i3 % 2048, co = r / 64, ci = r % 64;
            v = w3[(co * 64 + ci) * 9 + tap];
        } else {
            int i4 = idx - 165888;
            int tap = i4 / 512, r = i4 % 512, co = r / 32, ci = r % 32;
            if (co < 2) v = w4[(co * 32 + ci) * 25 + tap];
        }
        wr[idx] = f2bf(v);
    }
}

// ---------------------------------------------------------------------------
// 2) warp: bilinear + oob mask, fp64 coords; OUTPUT = bf16-pair dwords
//    XCD-bijective swizzle (validated R5: -64us)
// ---------------------------------------------------------------------------
__global__ __launch_bounds__(256) void warp_kernel(
    const float* __restrict__ feats, const double* __restrict__ flow_up,
    uint* __restrict__ wp)
{
#pragma clang fp contract(off)
    int raw = blockIdx.x;                        // 0..1919
    int eb  = (raw & 7) * 240 + (raw >> 3);      // bijective (1920%8==0)
    int g = eb / 960;                            // channel-group 0/1
    int idx = (eb % 960) * 256 + threadIdx.x;    // over B*H*W
    int x = idx % W;
    int y = (idx / W) % H;
    int b = idx / HW_;

    double f0 = flow_up[(size_t)(b * 2 + 0) * HW_ + y * W + x];
    double f1 = flow_up[(size_t)(b * 2 + 1) * HW_ + y * W + x];

    double stepx = 2.0 / (double)(W - 1);
    double stepy = 2.0 / (double)(H - 1);
    double gx = (x == W - 1) ? 1.0 : ((double)x * stepx + (-1.0));
    double gy = (y == H - 1) ? 1.0 : ((double)y * stepy + (-1.0));
    double cxs = 2.0 * 2.5 / (double)(W - 1);
    double cys = 2.0 * 2.5 / (double)(H - 1);
    double sx = gx + f0 * cxs;
    double sy = gy + f1 * cys;
    double px = (sx + 1.0) * 0.5 * (double)(W - 1);
    double py = (sy + 1.0) * 0.5 * (double)(H - 1);

    double pxc = px < 0.0 ? 0.0 : (px > (double)(W - 1) ? (double)(W - 1) : px);
    double pyc = py < 0.0 ? 0.0 : (py > (double)(H - 1) ? (double)(H - 1) : py);
    double x0 = floor(pxc), y0 = floor(pyc);
    double tx = pxc - x0, ty = pyc - y0;
    int x0i = (int)x0, y0i = (int)y0;
    int y1i = min(y0i + 1, H - 1);

    double fx0 = floor(px), fy0 = floor(py);
    double mtx = px - fx0, mty = py - fy0;
    double w00 = (1.0 - mtx) * (1.0 - mty);
    double w01 = mtx * (1.0 - mty);
    double w10 = (1.0 - mtx) * mty;
    double w11 = mtx * mty;
    double m = 0.0;
    double xi, yi;
    xi = fx0;       yi = fy0;
    if (xi >= 0.0 && xi <= (double)(W - 1) && yi >= 0.0 && yi <= (double)(H - 1)) m = m + w00;
    xi = fx0 + 1.0; yi = fy0;
    if (xi >= 0.0 && xi <= (double)(W - 1) && yi >= 0.0 && yi <= (double)(H - 1)) m = m + w01;
    xi = fx0;       yi = fy0 + 1.0;
    if (xi >= 0.0 && xi <= (double)(W - 1) && yi >= 0.0 && yi <= (double)(H - 1)) m = m + w10;
    xi = fx0 + 1.0; yi = fy0 + 1.0;
    if (xi >= 0.0 && xi <= (double)(W - 1) && yi >= 0.0 && yi <= (double)(H - 1)) m = m + w11;
    float mask = (m >= 1.0) ? 1.0f : 0.0f;

    float a00 = (float)((1.0 - tx) * (1.0 - ty)) * mask;
    float a01 = (float)(tx * (1.0 - ty)) * mask;
    float a10 = (float)((1.0 - tx) * ty) * mask;
    float a11 = (float)(tx * ty) * mask;

    // rebase so the two x-corners are a contiguous float2
    int base = min(x0i, W - 2);
    bool xe = (x0i == W - 1);                 // only then does corner0 sit at .y
    int r0 = y0i * W + base;
    int r1 = y1i * W + base;

    const float* img = feats + (size_t)(b * 2 + 1) * C * HW_;
    uint* dst = wp + (size_t)b * 64 * HW_ + y * W + x;
    #pragma unroll 4
    for (int c2 = g * 32; c2 < g * 32 + 32; ++c2) {
        const float* p0 = img + (size_t)(2 * c2) * HW_;
        const float* p1 = p0 + HW_;
        float2 L0 = *(const float2*)&p0[r0];
        float2 L1 = *(const float2*)&p0[r1];
        float2 M0 = *(const float2*)&p1[r0];
        float2 M1 = *(const float2*)&p1[r1];
        float v00 = xe ? L0.y : L0.x;
        float v10 = xe ? L1.y : L1.x;
        float u00 = xe ? M0.y : M0.x;
        float u10 = xe ? M1.y : M1.x;
        float lo = a00 * v00 + a01 * L0.y + a10 * v10 + a11 * L1.y;
        float hi = a00 * u00 + a01 * M0.y + a10 * u10 + a11 * M1.y;
        dst[(size_t)c2 * HW_] = pack2bf(lo, hi);
    }
}

// ---------------------------------------------------------------------------
// 4) correlation via MFMA — R6 version (best measured). SP=42 pad, stage 65
//    pad, XCD swizzle. (R7 prefetch regressed; y-tile-4 regressed.)
// ---------------------------------------------------------------------------
__global__ __launch_bounds__(256, 4) void corr_kernel(
    const float* __restrict__ feats, const uint* __restrict__ wp,
    uint* __restrict__ corrb)
{
    constexpr int SP = 42;                             // padded stride (halfs)
    __shared__ unsigned short lds[(320 + 64) * SP];    // 32256 B
    float* stage = (float*)lds;                        // 49 x 65 f32 epilogue

    int raw = blockIdx.x;
    int t = (raw & 7) * 480 + (raw >> 3);              // bijective (3840%8==0)
    int xt = t % 10, yg = (t / 10) % 96, b = t / 960;
    int x0 = xt * 32, y0 = yg * 2;
    int tid = threadIdx.x;
    int lane = tid & 63, wave = tid >> 6;
    int lanelo = lane & 15, laneq = (lane >> 4) & 3;
    int h = wave & 1, yr = wave >> 1;

    // per-lane window-tile addresses (halfs), hoisted out of the ck loop
    int baddr[10], di_t[10], c_t[10];
    #pragma unroll
    for (int tt = 0; tt < 10; ++tt) {
        int p = tt * 16 + lanelo;
        int di = p / 22, cc = p - di * 22;
        di_t[tt] = di; c_t[tt] = cc;
        int addr = ((yr + di) * 40 + h * 16 + cc + 1) * SP + laneq * 8;
        baddr[tt] = (di > 6) ? 0 : addr;
    }
    int qaddr = (320 + yr * 32 + h * 16 + lanelo) * SP + laneq * 8;

    f32x4 acc[10];
    #pragma unroll
    for (int tt = 0; tt < 10; ++tt) acc[tt] = f32x4{0.f, 0.f, 0.f, 0.f};

    const uint* wpb = wp + (size_t)b * 64 * HW_;
    const float* f1b = feats + (size_t)(b * 2) * C * HW_;

    for (int ck = 0; ck < 4; ++ck) {
        if (ck) __syncthreads();
        // stage K chunk: 8 rows x 10 quads x 16 pairs
        #pragma unroll
        for (int i = 0; i < 5; ++i) {
            int u = tid + i * 256;
            int q = u % 10, pp = (u / 10) & 15, r = u / 160;
            int gy = y0 - 3 + r, gx0 = x0 - 4 + 4 * q;
            uint4 v = {0, 0, 0, 0};
            if (gy >= 0 && gy < H && gx0 >= 0 && gx0 < W)
                v = *(const uint4*)&wpb[(size_t)(ck * 16 + pp) * HW_ + gy * W + gx0];
            int pxb = (r * 40 + 4 * q) * SP + 2 * pp;
            *(uint*)&lds[pxb]          = v.x;
            *(uint*)&lds[pxb + SP]     = v.y;
            *(uint*)&lds[pxb + 2 * SP] = v.z;
            *(uint*)&lds[pxb + 3 * SP] = v.w;
        }
        // stage Q chunk: 64 px x 16 pairs, fp32 -> bf16
        #pragma unroll
        for (int i = 0; i < 4; ++i) {
            int u = tid + i * 256;
            int px = u & 63, pp = u >> 6;
            int gx = x0 + (px & 31), gy = y0 + (px >> 5);
            const float* p0 = f1b + (size_t)(ck * 32 + 2 * pp) * HW_ + gy * W + gx;
            *(uint*)&lds[(320 + px) * SP + 2 * pp] = pack2bf(p0[0], p0[HW_]);
        }
        __syncthreads();
        const short8 qf = *(const short8*)&lds[qaddr];
        #pragma unroll
        for (int tt = 0; tt < 10; ++tt) {
            const short8 kf = *(const short8*)&lds[baddr[tt]];
            acc[tt] = __builtin_amdgcn_mfma_f32_16x16x32_bf16(qf, kf, acc[tt], 0, 0, 0);
        }
    }
    __syncthreads();
    // scatter the valid band entries: S[i, p] -> stage[di*7+dj][px] (65-pad)
    #pragma unroll
    for (int tt = 0; tt < 10; ++tt) {
        int di = di_t[tt];
        #pragma unroll
        for (int reg = 0; reg < 4; ++reg) {
            int i = laneq * 4 + reg;
            int dj = c_t[tt] - i;
            if (di <= 6 && dj >= 0 && dj < 7)
                stage[(di * 7 + dj) * 65 + yr * 32 + h * 16 + i] = acc[tt][reg];
        }
    }
    __syncthreads();
    // leaky + /128 + bf16 pair-pack + store
    uint* outp = corrb + (size_t)b * 32 * HW_;
    #pragma unroll
    for (int i = 0; i < 8; ++i) {
        int u = tid + i * 256;
        int px = u & 63, k2 = u >> 6;
        int gx = x0 + (px & 31), gy = y0 + (px >> 5);
        float v0 = (2 * k2 < 49) ? stage[(2 * k2) * 65 + px] : 0.f;
        float v1 = (2 * k2 + 1 < 49) ? stage[(2 * k2 + 1) * 65 + px] : 0.f;
        v0 = v0 > 0.f ? v0 : 0.1f * v0;
        v1 = v1 > 0.f ? v1 : 0.1f * v1;
        outp[(size_t)k2 * HW_ + gy * W + gx] = pack2bf(v0 * (1.f / 128.f), v1 * (1.f / 128.f));
    }
}

// ---------------------------------------------------------------------------
// 5) 3x3 conv, 32x32x16 MFMA — R6 configs (256-thr; R8 128-thr TLP was null).
//    S2=21 pad + XCD swizzle.
// ---------------------------------------------------------------------------
template<int CINP, int COUTP, int WCO, int WROWS, int MG, int NR, int MINW>
__global__ __launch_bounds__(WCO * WROWS * 64, MINW) void conv3x3_kernel(
    const uint* __restrict__ in, const unsigned short* __restrict__ wr,
    const float* __restrict__ bias, uint* __restrict__ outp, int cpx)
{
    constexpr int NT = WCO * WROWS * 64;
    constexpr int TH = WROWS * NR;
    constexpr int RH = TH + 2;
    constexpr int RW = 40, S2 = 21;
    constexpr int CHUNKS = CINP / 32;
    __shared__ uint lds32[RH * RW * S2];

    int tid = threadIdx.x;
    int lane = tid & 63, wave = tid >> 6;
    int lane5 = lane & 31, kg = lane >> 5;
    int cow = (WCO == 1) ? 0 : (wave & 1);
    int rowg = (WCO == 1) ? wave : (wave >> 1);

    int raw = blockIdx.x;
    int bx = (raw & 7) * cpx + (raw >> 3);    // bijective XCD swizzle (grid%8==0)
    int xt = bx % 10;
    int yt = (bx / 10) % (H / TH);
    int b = bx / (10 * (H / TH));
    int tx0 = xt * 32, ty0 = yt * TH;
    int cob = cow * MG * 32;

    f32x16 acc[MG][NR];
    #pragma unroll
    for (int mg = 0; mg < MG; ++mg)
        #pragma unroll
        for (int nr = 0; nr < NR; ++nr)
            #pragma unroll
            for (int j = 0; j < 16; ++j) acc[mg][nr][j] = 0.f;

    const uint* inb = in + (size_t)b * (CINP / 2) * HW_;

    for (int ck = 0; ck < CHUNKS; ++ck) {
        if (ck) __syncthreads();
        constexpr int UNITS = RH * 10 * 16;
        for (int s = tid; s < UNITS; s += NT) {
            int q = s % 10;
            int pp = (s / 10) % 16;
            int r = s / 160;
            int gy = ty0 - 1 + r;
            int gx0 = tx0 - 4 + 4 * q;
            uint4 v = {0, 0, 0, 0};
            if (gy >= 0 && gy < H && gx0 >= 0 && gx0 < W)
                v = *(const uint4*)&inb[(size_t)(ck * 16 + pp) * HW_ + gy * W + gx0];
            int pbase = (r * RW + 4 * q) * S2 + pp;
            lds32[pbase]          = v.x;
            lds32[pbase + S2]     = v.y;
            lds32[pbase + 2 * S2] = v.z;
            lds32[pbase + 3 * S2] = v.w;
        }
        __syncthreads();

        for (int tap = 0; tap < 9; ++tap) {   // dynamic: keeps A-frag regs low
            int ky = tap / 3, kx = tap - ky * 3;
            short8 A[MG][2];
            #pragma unroll
            for (int mg = 0; mg < MG; ++mg)
                #pragma unroll
                for (int ks = 0; ks < 2; ++ks)
                    A[mg][ks] = *(const short8*)&wr[
                        ((size_t)tap * COUTP + cob + mg * 32 + lane5) * CINP +
                        ck * 32 + ks * 16 + kg * 8];
            #pragma unroll
            for (int nr = 0; nr < NR; ++nr) {
                int rr = rowg * NR + nr + ky;
                int col = lane5 + kx + 3;
                #pragma unroll
                for (int ks = 0; ks < 2; ++ks) {
                    const short8 Bf = *(const short8*)&lds32[(rr * RW + col) * S2 + ks * 8 + kg * 4];
                    #pragma unroll
                    for (int mg = 0; mg < MG; ++mg)
                        acc[mg][nr] = __builtin_amdgcn_mfma_f32_32x32x16_bf16(
                            A[mg][ks], Bf, acc[mg][nr], 0, 0, 0);
                }
            }
        }
    }

    // epilogue: C row = (reg&3) + 8*(reg>>2) + 4*kg; reg pairs -> even co pairs
    int xg = tx0 + lane5;
    #pragma unroll
    for (int mg = 0; mg < MG; ++mg)
        #pragma unroll
        for (int nr = 0; nr < NR; ++nr) {
            int ygl = ty0 + rowg * NR + nr;
            #pragma unroll
            for (int j = 0; j < 8; ++j) {
                int com = ((2 * j) & 3) + 8 * (j >> 1) + 4 * kg;
                int co = cob + mg * 32 + com;
                float v0 = acc[mg][nr][2 * j] + bias[co];
                float v1 = acc[mg][nr][2 * j + 1] + bias[co + 1];
                v0 = v0 > 0.f ? v0 : 0.1f * v0;
                v1 = v1 > 0.f ? v1 : 0.1f * v1;
                outp[((size_t)b * (COUTP / 2) + (co >> 1)) * HW_ + ygl * W + xg] =
                    pack2bf(v0, v1);
            }
        }
}

// ---------------------------------------------------------------------------
// 6) conv4 (5x5, cout 2 padded to 16, +bias +flow_up, fp32 out) — 16x16x32 MFMA
// ---------------------------------------------------------------------------
template<int CINP, int COUTP, int M_TILES, int N_TILES, int KS, int MINW>
__global__ __launch_bounds__(256, MINW) void conv_mfma_kernel(
    const uint* __restrict__ in, const unsigned short* __restrict__ wr,
    const float* __restrict__ bias, float* __restrict__ outp,
    const double* __restrict__ flow_up, int coutReal, int cpx)
{
    constexpr int CHUNK = 32;
    constexpr int PADK = KS / 2;
    constexpr int PX_GROUPS = 4 / M_TILES;
    constexpr int TH = PX_GROUPS * (N_TILES / 2);
    constexpr int RH = TH + KS - 1;
    constexpr int RW = 40;
    constexpr int S2 = 21;
    constexpr int CHUNKS = CINP / CHUNK;
    __shared__ uint lds32[RH * RW * S2];

    int tid = threadIdx.x;
    int lanelo = tid & 15, laneq = (tid >> 4) & 3, wave = tid >> 6;
    int m_idx = wave % M_TILES, pgroup = wave / M_TILES;
    int pg_row0 = pgroup * (N_TILES / 2);

    int raw = blockIdx.x;
    int bx = (raw & 7) * cpx + (raw >> 3);
    int xt = bx % 10;
    int yt = (bx / 10) % (H / TH);
    int b = bx / (10 * (H / TH));
    int tx0 = xt * 32, ty0 = yt * TH;
    int cob = m_idx * 16;

    f32x4 acc[N_TILES];
    #pragma unroll
    for (int n = 0; n < N_TILES; ++n) acc[n] = f32x4{0.f, 0.f, 0.f, 0.f};

    const uint* inb = in + (size_t)b * (CINP / 2) * HW_;

    for (int ck = 0; ck < CHUNKS; ++ck) {
        constexpr int UNITS = RH * (CHUNK / 2) * 10;
        for (int s = tid; s < UNITS; s += 256) {
            int q = s % 10;
            int pp = (s / 10) % (CHUNK / 2);
            int r = s / (10 * (CHUNK / 2));
            int gy = ty0 - PADK + r;
            int gx0 = tx0 - 4 + q * 4;
            uint4 v = {0, 0, 0, 0};
            if (gy >= 0 && gy < H && gx0 >= 0 && gx0 < W)
                v = *(const uint4*)&inb[(size_t)(ck * (CHUNK / 2) + pp) * HW_ + gy * W + gx0];
            int pbase = (r * RW + q * 4) * S2 + pp;
            lds32[pbase] = v.x;
            lds32[pbase + S2] = v.y;
            lds32[pbase + 2 * S2] = v.z;
            lds32[pbase + 3 * S2] = v.w;
        }
        __syncthreads();

        short8 afr[KS * KS];
        #pragma unroll
        for (int tap = 0; tap < KS * KS; ++tap)
            afr[tap] = *(const short8*)&wr[
                ((size_t)tap * COUTP + cob + lanelo) * CINP + ck * CHUNK + laneq * 8];

        for (int tap = 0; tap < KS * KS; ++tap) {
            int ky = tap / KS, kx = tap - ky * KS;
            #pragma unroll
            for (int n = 0; n < N_TILES; ++n) {
                int rr = pg_row0 + (n >> 1) + ky;
                int pxi = (n & 1) * 16 + lanelo + (4 - PADK) + kx;
                const short8 bf = *(const short8*)&lds32[(rr * RW + pxi) * S2 + laneq * 4];
                acc[n] = __builtin_amdgcn_mfma_f32_16x16x32_bf16(afr[tap], bf, acc[n], 0, 0, 0);
            }
        }
        __syncthreads();
    }

    #pragma unroll
    for (int n = 0; n < N_TILES; ++n) {
        int x = tx0 + (n & 1) * 16 + lanelo;
        int y = ty0 + pg_row0 + (n >> 1);
        #pragma unroll
        for (int j = 0; j < 4; ++j) {
            int co = cob + laneq * 4 + j;
            if (co < coutReal) {
                float v = acc[n][j] + bias[co];
                v += (float)flow_up[((size_t)(b * 2) + co) * HW_ + y * W + x];
                outp[((size_t)b * coutReal + co) * HW_ + y * W + x] = v;
            }
        }
    }
}

// ---------------------------------------------------------------------------
extern "C" void kernel_launch(void* const* d_in, const int* in_sizes, int n_in,
                              void* d_out, int out_size, void* d_ws, size_t ws_size,
                              hipStream_t stream)
{
    const float* feats = (const float*)d_in[0];
    const float* flow  = (const float*)d_in[1];
    const float* up_w  = (const float*)d_in[2];
    const float* w1 = (const float*)d_in[3];
    const float* b1 = (const float*)d_in[4];
    const float* w2 = (const float*)d_in[5];
    const float* b2 = (const float*)d_in[6];
    const float* w3 = (const float*)d_in[7];
    const float* b3 = (const float*)d_in[8];
    const float* w4 = (const float*)d_in[9];
    const float* b4 = (const float*)d_in[10];
    float* out = (float*)d_out;

    char* ws = (char*)d_ws;
    double* flow_up = (double*)ws;                    // 3,932,160 B
    uint* wp    = (uint*)(ws + 3932160);              // warped bf16-pairs / h1
    uint* h1    = (uint*)(ws + 3932160);
    uint* corrb = (uint*)(ws + 66846720);             // corr / h2
    uint* h2    = corrb;
    uint* h3    = (uint*)(ws + 98304000);
    unsigned short* wr = (unsigned short*)(ws + 114032640);
    unsigned short* wr1 = wr;
    unsigned short* wr2 = wr + 73728;
    unsigned short* wr3 = wr + 147456;
    unsigned short* wr4 = wr + 165888;

    // fused upflow (blocks 0..1919) + weight repack (blocks 1920..2618)
    prepass_kernel<<<2619, 256, 0, stream>>>(flow, up_w, flow_up,
                                             w1, w2, w3, w4, wr);
    warp_kernel<<<1920, 256, 0, stream>>>(feats, flow_up, wp);
    corr_kernel<<<3840, 256, 0, stream>>>(feats, wp, corrb);

    // conv1: cin 64(pad49) -> cout 128. grid 1920 -> cpx 240
    conv3x3_kernel<64, 128, 2, 2, 2, 2, 3>
        <<<1920, 256, 0, stream>>>(corrb, wr1, b1, h1, 240);
    // conv2: cin 128 -> cout 64. grid 960 -> cpx 120
    conv3x3_kernel<128, 64, 1, 4, 2, 2, 3>
        <<<960, 256, 0, stream>>>(h1, wr2, b2, h2, 120);
    // conv3: cin 64 -> cout 32. grid 960 -> cpx 120
    conv3x3_kernel<64, 32, 1, 4, 1, 2, 3>
        <<<960, 256, 0, stream>>>(h2, wr3, b3, h3, 120);
    // conv4: cin 32 -> cout 2 (pad 16), 5x5, fp32 out + bias + flow_up
    conv_mfma_kernel<32, 16, 1, 2, 5, 2>
        <<<1920, 256, 0, stream>>>(h3, wr4, b4, out, flow_up, 2, 240);
}